// Round 2
// baseline (1176.978 us; speedup 1.0000x reference)
//
#include <hip/hip_runtime.h>
#include <cmath>

#define D 64
#define BLK 256
#define KC 128         // k-chunk staged in LDS
#define MARGIN 1e-2f   // fp32 top-2 gap below this -> fp64 refine (fp32 err bound ~2.5e-4)
#define NPMAX 8        // max partitioned copies of scatter accumulators

// ---------------- K0: wn[k] = 0.5*||w_k||^2 (fp32) ----------------
__global__ void k_wn(const float* __restrict__ w, float* __restrict__ wn, int K) {
    int k = blockIdx.x * blockDim.x + threadIdx.x;
    if (k >= K) return;
    float s = 0.f;
    for (int d = 0; d < D; ++d) {
        float v = w[(size_t)d * K + k];
        s = fmaf(v, v, s);
    }
    wn[k] = 0.5f * s;
}

// ---------------- K2: fp32 argmax of t_k = x.w_k - wn_k, top-2 margin flag ----------------
// PPT=1: x row (64 floats) provably register-resident under the 128-VGPR cap.
__global__ __launch_bounds__(BLK, 4) void k_assign(
    const float* __restrict__ x, const float* __restrict__ w,
    const float* __restrict__ wn, unsigned int* __restrict__ idx_out,
    float* __restrict__ quant, int N, int K)
{
    __shared__ float lds_w[KC][D + 4];   // 128*68*4 = 34816 B
    __shared__ float lds_wn[KC];
    const int tid = threadIdx.x;
    const long long n = (long long)blockIdx.x * BLK + tid;
    const long long nn = (n < N) ? n : (N - 1);

    // x row -> registers (16 float4 = 64 VGPRs), hoisted before any barrier
    float4 xa[D / 4];
    {
        const float4* xr = (const float4*)(x + nn * D);
        #pragma unroll
        for (int i = 0; i < D / 4; ++i) xa[i] = xr[i];
    }

    float best = -INFINITY, sec = -INFINITY;
    int bi = 0;

    const int kown  = tid & (KC - 1);     // code this thread stages
    const int dhalf = tid >> 7;           // 0 or 1: which 32-dim half

    for (int k0 = 0; k0 < K; k0 += KC) {
        __syncthreads();
        // stage chunk: 256 threads cover 128 codes x 2 dim-halves
        #pragma unroll 8
        for (int i = 0; i < 32; ++i) {
            int d = dhalf * 32 + i;
            lds_w[kown][d] = w[(size_t)d * K + (k0 + kown)];
        }
        if (dhalf == 0) lds_wn[kown] = wn[k0 + kown];
        __syncthreads();

        for (int kc = 0; kc < KC; ++kc) {
            const float4* wr = (const float4*)(&lds_w[kc][0]);  // broadcast reads
            float da = -lds_wn[kc], db = 0.f;   // 2 independent chains
            #pragma unroll
            for (int i = 0; i < D / 8; ++i) {
                float4 wv0 = wr[2 * i], wv1 = wr[2 * i + 1];
                float4 xv0 = xa[2 * i], xv1 = xa[2 * i + 1];
                da = fmaf(xv0.x, wv0.x, da);
                db = fmaf(xv1.x, wv1.x, db);
                da = fmaf(xv0.y, wv0.y, da);
                db = fmaf(xv1.y, wv1.y, db);
                da = fmaf(xv0.z, wv0.z, da);
                db = fmaf(xv1.z, wv1.z, db);
                da = fmaf(xv0.w, wv0.w, da);
                db = fmaf(xv1.w, wv1.w, db);
            }
            float dot = da + db;
            // strict > keeps smallest k on exact ties (argmax first-occurrence)
            bool g = dot > best;
            sec  = g ? best : fmaxf(sec, dot);
            best = g ? dot : best;
            bi   = g ? (k0 + kc) : bi;
        }
    }

    if (n < N) {
        unsigned flag = ((best - sec) < MARGIN) ? 0x80000000u : 0u;
        idx_out[n] = (unsigned)bi | flag;
        const float* wc = w + bi;
        float4* qd = (float4*)(quant + n * D);
        #pragma unroll
        for (int i = 0; i < D / 4; ++i) {
            float4 q;
            q.x = wc[(size_t)(4 * i + 0) * K];
            q.y = wc[(size_t)(4 * i + 1) * K];
            q.z = wc[(size_t)(4 * i + 2) * K];
            q.w = wc[(size_t)(4 * i + 3) * K];
            qd[i] = q;
        }
    }
}

// ---------------- K3: fp64 exact rescan of flagged points (rare) ----------------
__global__ void k_refine(const float* __restrict__ x, const float* __restrict__ w,
                         unsigned int* __restrict__ idx_io, float* __restrict__ quant,
                         int N, int K)
{
    const int gtid = blockIdx.x * blockDim.x + threadIdx.x;
    const int lane = threadIdx.x & 63;
    const long long wave = gtid >> 6;
    const long long nwaves = (long long)(gridDim.x * blockDim.x) >> 6;

    for (long long base = wave * 64; base < N; base += nwaves * 64) {
        long long nl = base + lane;
        unsigned v = (nl < (long long)N) ? idx_io[nl] : 0u;
        unsigned long long flags = __ballot(v >> 31);
        while (flags) {
            int j = __ffsll(flags) - 1;
            flags &= flags - 1;
            long long p = base + j;
            float xr[D];
            #pragma unroll 8
            for (int d = 0; d < D; ++d) xr[d] = x[p * D + d];
            double bt = -1e300;
            int bk = 0;
            for (int k = lane; k < K; k += 64) {   // ascending k per lane; strict > = first-occurrence
                double t = 0.0, s = 0.0;
                #pragma unroll 8
                for (int d = 0; d < D; ++d) {
                    double wd = (double)w[(size_t)d * K + k];
                    t = fma((double)xr[d], wd, t);
                    s = fma(wd, wd, s);
                }
                t -= 0.5 * s;
                if (t > bt) { bt = t; bk = k; }
            }
            #pragma unroll
            for (int off = 32; off > 0; off >>= 1) {
                double ot = __shfl_down(bt, off);
                int    ok = __shfl_down(bk, off);
                if (ot > bt || (ot == bt && ok < bk)) { bt = ot; bk = ok; }
            }
            int fk = __shfl(bk, 0);
            if (lane == 0) idx_io[p] = (unsigned)fk;     // clear flag
            quant[p * D + lane] = w[(size_t)lane * K + fk];
        }
    }
}

// ---------------- K4: scatter x into NP private [K][D] partial sums + counts ----------------
__global__ void k_scatter(const float* __restrict__ x, const unsigned int* __restrict__ idx,
                          float* __restrict__ cs, float* __restrict__ cn, int N, int K, int NP)
{
    const int gtid = blockIdx.x * blockDim.x + threadIdx.x;
    const int lane = threadIdx.x & 63;
    const long long wave = gtid >> 6;
    const long long nwaves = (long long)(gridDim.x * blockDim.x) >> 6;
    const int part = blockIdx.x % NP;
    float* csp = cs + (size_t)part * K * D;
    float* cnp = cn + (size_t)part * K;
    for (long long p = wave; p < N; p += nwaves) {
        unsigned k = idx[p] & 0x7fffffffu;
        float v = x[p * D + lane];
        unsafeAtomicAdd(&csp[(size_t)k * D + lane], v);   // coalesced 256B burst per wave
        if (lane == 0) unsafeAtomicAdd(&cnp[k], 1.0f);
    }
}

// ---------------- K5: reduce NP partials + EMA combine -> new_w [D][K] ----------------
__global__ void k_combine(const float* __restrict__ c_sum, const float* __restrict__ c_n,
                          const float* __restrict__ cs, const float* __restrict__ cn,
                          float* __restrict__ outw, int K, int NP)
{
    int i = blockIdx.x * blockDim.x + threadIdx.x;   // i = d*K + k
    if (i >= D * K) return;
    int k = i % K;
    int d = i / K;
    float s = 0.f, nk = 0.f;
    for (int p = 0; p < NP; ++p) {
        s  += cs[(size_t)p * K * D + (size_t)k * D + d];
        nk += cn[(size_t)p * K + k];
    }
    const float g  = 0.99f;
    const float og = (float)(1.0 - 0.99);
    float ns = c_sum[i] * g + s * og;
    float nn = c_n[k] * g + nk * og;
    outw[i] = ns / nn;
}

extern "C" void kernel_launch(void* const* d_in, const int* in_sizes, int n_in,
                              void* d_out, int out_size, void* d_ws, size_t ws_size,
                              hipStream_t stream)
{
    const float* x     = (const float*)d_in[0];
    const float* w     = (const float*)d_in[1];
    const float* c_sum = (const float*)d_in[2];
    const float* c_n   = (const float*)d_in[3];
    const int N = in_sizes[0] / D;
    const int K = in_sizes[3];

    float* quant = (float*)d_out;                      // N*D
    float* outw  = (float*)d_out + (size_t)N * D;      // D*K

    // pick NP partitions that fit the workspace
    size_t fixed = (size_t)N * 4 + (size_t)K * 4;      // idx + wn
    int NP = NPMAX;
    while (NP > 1 && fixed + (size_t)NP * K * (D + 1) * 4 > ws_size) NP >>= 1;

    char* ws = (char*)d_ws;
    unsigned* idx = (unsigned*)ws;                                     // N ints
    float* cs = (float*)(ws + (size_t)N * 4);                          // NP*K*D
    float* cn = cs + (size_t)NP * K * D;                               // NP*K
    float* wn = cn + (size_t)NP * K;                                   // K

    hipMemsetAsync(cs, 0, (size_t)NP * K * (D + 1) * sizeof(float), stream);
    k_wn<<<(K + 255) / 256, 256, 0, stream>>>(w, wn, K);

    int grid_assign = (N + BLK - 1) / BLK;                             // 1024 blocks
    k_assign<<<grid_assign, BLK, 0, stream>>>(x, w, wn, idx, quant, N, K);

    k_refine<<<256, 256, 0, stream>>>(x, w, idx, quant, N, K);
    k_scatter<<<512, 256, 0, stream>>>(x, idx, cs, cn, N, K, NP);
    k_combine<<<(D * K + 255) / 256, 256, 0, stream>>>(c_sum, c_n, cs, cn, outw, K, NP);
}